// Round 9
// baseline (208.474 us; speedup 1.0000x reference)
//
#include <hip/hip_runtime.h>
#include <math.h>

#define NROWS 8192
#define DIN   60
#define DZ    16
#define NC    10

#define LOG2E 1.4426950408889634f

// K2 tiling: block = 256 thr (4 waves), each wave owns 16 rows (1 i-tile).
// RB=64 rows/block, CJ=512 cols/chunk -> grid 128*16 = 2048 blocks
// = 8 blocks/CU x 4 waves = 32 waves/CU when VGPR <= 64.
#define RB    64
#define CJ    512
#define NRB   (NROWS / RB)    // 128 row blocks
#define NCH   (NROWS / CJ)    // 16 col chunks
#define WAVES 4

typedef short bf16x8 __attribute__((ext_vector_type(8)));
typedef float f32x4  __attribute__((ext_vector_type(4)));

__device__ __forceinline__ unsigned int bfr(float f) {
    // bf16 bits, round-half-up
    return (__float_as_uint(f) + 0x8000u) >> 16;
}

// ---------------------------------------------------------------------------
// K1 (fused): z = fc2(fc1(x)); zb = bf16(z*sqrt(2*temp*log2e)) zero-padded to
// 32 K-slots; bbf_i = log2e*(temp*||z||^2 - theta/2); xT = bf16 transpose of
// x augmented with a ones-column (row 60) for the rowsum.
// ---------------------------------------------------------------------------
__global__ __launch_bounds__(64) void k1_all(
    const float* __restrict__ x,
    const float* __restrict__ w1, const float* __restrict__ b1,
    const float* __restrict__ w2, const float* __restrict__ b2,
    const float* __restrict__ temp_p, const float* __restrict__ theta_p,
    unsigned short* __restrict__ zb, float* __restrict__ bbf,
    unsigned short* __restrict__ xT)
{
    int i = blockIdx.x * 64 + threadIdx.x;

    float xr[DIN];
    const float4* xp = reinterpret_cast<const float4*>(x + (size_t)i * DIN);
    #pragma unroll
    for (int c = 0; c < 15; ++c) {
        float4 v = xp[c];
        xr[c*4+0] = v.x; xr[c*4+1] = v.y; xr[c*4+2] = v.z; xr[c*4+3] = v.w;
    }

    float n1[32];
    #pragma unroll
    for (int o = 0; o < 32; ++o) {
        float acc = b1[o];
        #pragma unroll
        for (int k = 0; k < DIN; ++k) acc = fmaf(w1[o*DIN+k], xr[k], acc);
        n1[o] = acc;
    }

    float z[DZ];
    float sq = 0.0f;
    #pragma unroll
    for (int u = 0; u < DZ; ++u) {
        float acc = b2[u];
        #pragma unroll
        for (int o = 0; o < 32; ++o) acc = fmaf(w2[u*32+o], n1[o], acc);
        z[u] = acc;
        sq = fmaf(acc, acc, sq);
    }

    float temp  = *temp_p;
    float theta = *theta_p;
    float s = sqrtf(2.0f * temp * LOG2E);

    unsigned int p[8];
    #pragma unroll
    for (int u = 0; u < 8; ++u) {
        unsigned int lo = bfr(z[2*u]   * s);
        unsigned int hi = bfr(z[2*u+1] * s);
        p[u] = lo | (hi << 16);
    }
    uint4* dst = reinterpret_cast<uint4*>(zb + (size_t)i * 32);
    dst[0] = make_uint4(p[0], p[1], p[2], p[3]);
    dst[1] = make_uint4(p[4], p[5], p[6], p[7]);
    dst[2] = make_uint4(0, 0, 0, 0);     // zero K-slots 16..31
    dst[3] = make_uint4(0, 0, 0, 0);

    bbf[i] = LOG2E * fmaf(temp, sq, -0.5f * theta);

    // transpose write (lane-contiguous in i -> coalesced stores)
    #pragma unroll
    for (int c = 0; c < DIN; ++c)
        xT[(size_t)c * NROWS + i] = (unsigned short)bfr(xr[c]);
    xT[(size_t)60 * NROWS + i] = 0x3F80;  // 1.0
    xT[(size_t)61 * NROWS + i] = 0;
    xT[(size_t)62 * NROWS + i] = 0;
    xT[(size_t)63 * NROWS + i] = 0;
}

// ---------------------------------------------------------------------------
// K2: MFMA flash-style pairwise, 1 i-tile (16 rows) per wave for 32 waves/CU.
//   Swapped QK^T: S' = mfma(z_j, z_i) -> C col = i (lane&15), row = j
//   (4*(lane>>4)+reg). sigmoid -> bf16 packed -> wave-private LDS (ull-typed
//   both ways + __threadfence_block; r8-proven hardening) -> A-frag for PV:
//   H[i][n] += P[i][j] @ xT-aug. Rowsum = col 60. Diag zeroed; k3 re-adds.
//   Epilogue: natural register layout, flat [ch][rb][wave][slot=nt*4+r][lane]
//   -> 16 stores x 256 B contiguous. k3_fused de-swizzles via LDS.
// ---------------------------------------------------------------------------
__global__ __launch_bounds__(256, 8) void k2_mfma(
    const unsigned short* __restrict__ zb, const float* __restrict__ bbf,
    const unsigned short* __restrict__ xT, const float* __restrict__ theta_p,
    float* __restrict__ hacc)   // [NCH][NRB][WAVES][16][64] floats
{
    __shared__ unsigned long long sP[WAVES * 160];   // 1280 B per wave

    const int tid  = threadIdx.x;
    const int lane = tid & 63, wave = tid >> 6;
    const int q = lane & 15, g = lane >> 4;
    const int rb = blockIdx.x & (NRB - 1);
    const int ch = blockIdx.x >> 7;            // NRB == 128
    const int i0 = rb * RB + wave * 16;
    const int j0 = ch * CJ;

    bf16x8 zbi = *reinterpret_cast<const bf16x8*>(zb + (size_t)(i0 + q) * 32 + g*8);
    float  bi  = bbf[i0 + q];
    const float nclamp = -(*theta_p) * LOG2E;
    const f32x4 z4 = {0.0f, 0.0f, 0.0f, 0.0f};

    f32x4 H[4];
    #pragma unroll
    for (int nt = 0; nt < 4; ++nt) H[nt] = z4;

    unsigned long long* myP = sP + wave * 160;

    for (int jp = 0; jp < CJ / 32; ++jp) {
        // ---- phase 1: QK^T + sigmoid + pack -> LDS (ull writes) ----
        #pragma unroll
        for (int half = 0; half < 2; ++half) {
            const int gj = j0 + jp*32 + half*16;
            bf16x8 za = *reinterpret_cast<const bf16x8*>(zb + (size_t)(gj + q) * 32 + g*8);
            f32x4  bj = *reinterpret_cast<const f32x4*>(bbf + gj + 4*g);
            f32x4 S = __builtin_amdgcn_mfma_f32_16x16x32_bf16(za, zbi, z4, 0, 0, 0);
            unsigned int ur[4];
            #pragma unroll
            for (int r = 0; r < 4; ++r) {
                float n = (bi + bj[r]) - S[r];
                n = fmaxf(n, nclamp);
                float P = __builtin_amdgcn_rcpf(1.0f + __builtin_amdgcn_exp2f(n));
                if (i0 == gj && q == 4*g + r) P = 0.0f;  // diag
                ur[r] = __float_as_uint(P) + 0x8000u;
            }
            unsigned int pk0 = (ur[0] >> 16) | (ur[1] & 0xFFFF0000u);
            unsigned int pk1 = (ur[2] >> 16) | (ur[3] & 0xFFFF0000u);
            // byte layout: q*80 + half*32 + g*8  (ull index = /8)
            myP[q*10 + half*4 + g] = ((unsigned long long)pk1 << 32) | pk0;
        }
        __threadfence_block();   // lgkmcnt fence: wave-local LDS writes complete

        // ---- phase 2: LDS -> A-frag (ull reads), PV MFMA ----
        const int jb = j0 + jp*32;
        bf16x8 pa;
        {
            union { unsigned long long u[2]; bf16x8 v; } pu;
            pu.u[0] = myP[q*10 + g*2];      // byte: q*80 + g*16
            pu.u[1] = myP[q*10 + g*2 + 1];
            pa = pu.v;
        }
        #pragma unroll
        for (int nt = 0; nt < 4; ++nt) {
            bf16x8 xb = *reinterpret_cast<const bf16x8*>(
                xT + (size_t)(nt*16 + q) * NROWS + jb + g*8);
            H[nt] = __builtin_amdgcn_mfma_f32_16x16x32_bf16(pa, xb, H[nt], 0, 0, 0);
        }
    }

    // epilogue: natural-layout flat store, each inst = 256 B contiguous
    float* regout = hacc + (((size_t)(ch * NRB + rb) * WAVES + wave) * 16) * 64;
    #pragma unroll
    for (int nt = 0; nt < 4; ++nt)
        #pragma unroll
        for (int r = 0; r < 4; ++r)
            regout[(nt*4 + r) * 64 + lane] = H[nt][r];
}

// ---------------------------------------------------------------------------
// K3 (fused reduce + head): block b owns k2 wave-chunk (rb=b>>2, wv=b&3)
//   = rows [b*16, b*16+16). Phase A: 256 thr each own one float4 of the
//   1024-float chunk; sum over NCH chunks (fully coalesced 4 KB/iter),
//   de-swizzle into LDS h[16][64]. Phase B: 16 lanes finish one row each:
//   +x_i/+1 exact diagonal, normalize, fc3, fc6, softmax.
//   Decode (f = tid*4): lane=f&63, slot=(f>>6)&15;
//   i_local = (lane>>4)*4 + (slot&3); col = ((slot>>2)&3)*16 + (lane&15).
// ---------------------------------------------------------------------------
__global__ __launch_bounds__(256) void k3_fused(
    const float* __restrict__ hacc,
    const float* __restrict__ x,
    const float* __restrict__ w3, const float* __restrict__ b3,
    const float* __restrict__ w6, const float* __restrict__ b6,
    float* __restrict__ out)
{
    __shared__ float sh[16][64];

    const int tid = threadIdx.x;
    const int b   = blockIdx.x;

    // ---- phase A: reduce + de-swizzle ----
    {
        const float4* src = reinterpret_cast<const float4*>(
            hacc + (size_t)b * 1024) + tid;
        float4 s = make_float4(0.0f, 0.0f, 0.0f, 0.0f);
        #pragma unroll 8
        for (int ch = 0; ch < NCH; ++ch) {
            float4 v = src[(size_t)ch * (NRB * WAVES * 16 * 64 / 4)];
            s.x += v.x; s.y += v.y; s.z += v.z; s.w += v.w;
        }
        const int f    = tid * 4;
        const int lane = f & 63;
        const int slot = (f >> 6) & 15;
        const int il   = (lane >> 4) * 4 + (slot & 3);
        const int cl   = ((slot >> 2) & 3) * 16 + (lane & 15);
        *reinterpret_cast<float4*>(&sh[il][cl]) = s;
    }
    __syncthreads();

    // ---- phase B: head, one row per lane (16 active) ----
    if (tid < 16) {
        const int row = b * 16 + tid;
        const float* hi = sh[tid];
        const float* xi = x + (size_t)row * DIN;

        float rd = __builtin_amdgcn_rcpf(hi[60] + 1.0f);

        float h[DIN];
        #pragma unroll
        for (int k = 0; k < DIN; ++k) h[k] = (hi[k] + xi[k]) * rd;

        float g[8];
        #pragma unroll
        for (int o = 0; o < 8; ++o) {
            float a = b3[o];
            #pragma unroll
            for (int k = 0; k < DIN; ++k) a = fmaf(w3[o*DIN+k], h[k], a);
            g[o] = a;
        }

        float l[NC];
        float m = -3.0e38f;
        #pragma unroll
        for (int c = 0; c < NC; ++c) {
            float a = b6[c];
            #pragma unroll
            for (int o = 0; o < 8; ++o) a = fmaf(w6[c*8+o], g[o], a);
            l[c] = a;
            m = fmaxf(m, a);
        }
        float e[NC];
        float sum = 0.0f;
        #pragma unroll
        for (int c = 0; c < NC; ++c) {
            e[c] = __builtin_amdgcn_exp2f((l[c] - m) * LOG2E);
            sum += e[c];
        }
        float rsum = __builtin_amdgcn_rcpf(sum);
        #pragma unroll
        for (int c = 0; c < NC; ++c) out[(size_t)row * NC + c] = e[c] * rsum;
    }
}

// ---------------------------------------------------------------------------
extern "C" void kernel_launch(void* const* d_in, const int* in_sizes, int n_in,
                              void* d_out, int out_size, void* d_ws, size_t ws_size,
                              hipStream_t stream)
{
    const float* x     = (const float*)d_in[0];
    const float* w1    = (const float*)d_in[1];
    const float* b1    = (const float*)d_in[2];
    const float* w2    = (const float*)d_in[3];
    const float* b2    = (const float*)d_in[4];
    const float* w3    = (const float*)d_in[5];
    const float* b3    = (const float*)d_in[6];
    const float* w6    = (const float*)d_in[7];
    const float* b6    = (const float*)d_in[8];
    const float* temp  = (const float*)d_in[9];
    const float* theta = (const float*)d_in[10];
    float* out = (float*)d_out;

    // ws carve-up: 0.5 + 0.03 + 1 + 32 MiB = 33.5 MiB (ws >= 67 MB proven)
    char* p = (char*)d_ws;
    unsigned short* zbuf = (unsigned short*)p;  p += (size_t)NROWS * 32 * 2;      // 512 KiB
    float*          bbf  = (float*)p;           p += (size_t)NROWS * 4;           // 32 KiB
    unsigned short* xT   = (unsigned short*)p;  p += (size_t)64 * NROWS * 2;      // 1 MiB
    float*          hacc = (float*)p;           // [NCH][NRB][4][16][64] = 32 MiB

    k1_all  <<<NROWS / 64, 64, 0, stream>>>(x, w1, b1, w2, b2, temp, theta, zbuf, bbf, xT);
    k2_mfma <<<NRB * NCH, 256, 0, stream>>>(zbuf, bbf, xT, theta, hacc);
    k3_fused<<<NROWS / 16, 256, 0, stream>>>(hacc, x, w3, b3, w6, b6, out);
}

// Round 10
// 179.906 us; speedup vs baseline: 1.1588x; 1.1588x over previous
//
#include <hip/hip_runtime.h>
#include <math.h>

#define NROWS 8192
#define DIN   60
#define DZ    16
#define NC    10

#define LOG2E 1.4426950408889634f

// K2 tiling: block = 256 thr (4 waves), each wave owns 32 rows (2 i-tiles)
// [r8-proven shape]. RB=128 rows/block, CJ=256 cols/chunk ->
// grid 64*32 = 2048 blocks = 8 blocks/CU x 4 waves = 32 waves/CU (no forced
// launch bounds -- r5/r9 lesson: occupancy via grid, not register squeezing).
#define RB    128
#define CJ    256
#define NRB   (NROWS / RB)    // 64 row blocks
#define NCH   (NROWS / CJ)    // 32 col chunks
#define WAVES 4

// partials chunk stride: 2 MiB + 4 KiB pad (de-camp power-of-2 channel stride)
#define CHPAD (NROWS * 64 + 1024)   // floats

typedef short bf16x8 __attribute__((ext_vector_type(8)));
typedef float f32x4  __attribute__((ext_vector_type(4)));

__device__ __forceinline__ unsigned int bfr(float f) {
    // bf16 bits, round-half-up
    return (__float_as_uint(f) + 0x8000u) >> 16;
}

// ---------------------------------------------------------------------------
// K1 (fused): z = fc2(fc1(x)); zb[i][0..15] = bf16(z*sqrt(2*temp*log2e))
// (16 shorts/row now; K-slots 16..31 are synthesized as zero fragments in k2);
// bbf_i = log2e*(temp*||z||^2 - theta/2); xT = bf16 transpose of x augmented
// with a ones-column (row 60).
// ---------------------------------------------------------------------------
__global__ __launch_bounds__(64) void k1_all(
    const float* __restrict__ x,
    const float* __restrict__ w1, const float* __restrict__ b1,
    const float* __restrict__ w2, const float* __restrict__ b2,
    const float* __restrict__ temp_p, const float* __restrict__ theta_p,
    unsigned short* __restrict__ zb, float* __restrict__ bbf,
    unsigned short* __restrict__ xT)
{
    int i = blockIdx.x * 64 + threadIdx.x;

    float xr[DIN];
    const float4* xp = reinterpret_cast<const float4*>(x + (size_t)i * DIN);
    #pragma unroll
    for (int c = 0; c < 15; ++c) {
        float4 v = xp[c];
        xr[c*4+0] = v.x; xr[c*4+1] = v.y; xr[c*4+2] = v.z; xr[c*4+3] = v.w;
    }

    float n1[32];
    #pragma unroll
    for (int o = 0; o < 32; ++o) {
        float acc = b1[o];
        #pragma unroll
        for (int k = 0; k < DIN; ++k) acc = fmaf(w1[o*DIN+k], xr[k], acc);
        n1[o] = acc;
    }

    float z[DZ];
    float sq = 0.0f;
    #pragma unroll
    for (int u = 0; u < DZ; ++u) {
        float acc = b2[u];
        #pragma unroll
        for (int o = 0; o < 32; ++o) acc = fmaf(w2[u*32+o], n1[o], acc);
        z[u] = acc;
        sq = fmaf(acc, acc, sq);
    }

    float temp  = *temp_p;
    float theta = *theta_p;
    float s = sqrtf(2.0f * temp * LOG2E);

    unsigned int p[8];
    #pragma unroll
    for (int u = 0; u < 8; ++u) {
        unsigned int lo = bfr(z[2*u]   * s);
        unsigned int hi = bfr(z[2*u+1] * s);
        p[u] = lo | (hi << 16);
    }
    uint4* dst = reinterpret_cast<uint4*>(zb + (size_t)i * 16);
    dst[0] = make_uint4(p[0], p[1], p[2], p[3]);
    dst[1] = make_uint4(p[4], p[5], p[6], p[7]);

    bbf[i] = LOG2E * fmaf(temp, sq, -0.5f * theta);

    // transpose write (lane-contiguous in i -> coalesced stores)
    #pragma unroll
    for (int c = 0; c < DIN; ++c)
        xT[(size_t)c * NROWS + i] = (unsigned short)bfr(xr[c]);
    xT[(size_t)60 * NROWS + i] = 0x3F80;  // 1.0
    xT[(size_t)61 * NROWS + i] = 0;
    xT[(size_t)62 * NROWS + i] = 0;
    xT[(size_t)63 * NROWS + i] = 0;
}

// ---------------------------------------------------------------------------
// K2: MFMA flash-style pairwise (r8-proven per-wave shape: 2 i-tiles/wave,
// VGPR ~40 naturally; occupancy from 2048-block grid = 32 waves/CU).
//   Swapped QK^T: S' = mfma(z_j, z_i) -> C col = i (lane&15), row = j
//   (4*(lane>>4)+reg). K-slots 16..31 of A/B fragments are zero (lanes g>=2
//   supply a zero fragment -- zb stores only 16 shorts/row).
//   sigmoid -> bf16 packed -> wave-private LDS (ull-typed both ways +
//   __threadfence_block; r8-proven) -> A-frag for PV:
//   H[i][n] += P[i][j] @ xT-aug. Rowsum = col 60. Diag zeroed; k3 re-adds.
//   Epilogue: natural register layout, flat [ch(pad)][rb][wave][slot][lane]
//   -> 32 stores x 256 B contiguous.
// ---------------------------------------------------------------------------
__global__ __launch_bounds__(256, 4) void k2_mfma(
    const unsigned short* __restrict__ zb, const float* __restrict__ bbf,
    const unsigned short* __restrict__ xT, const float* __restrict__ theta_p,
    float* __restrict__ hacc)   // [NCH][CHPAD] floats
{
    __shared__ unsigned long long sP[WAVES * 320];   // 2560 B per wave

    const int tid  = threadIdx.x;
    const int lane = tid & 63, wave = tid >> 6;
    const int q = lane & 15, g = lane >> 4;
    const int rb = blockIdx.x & (NRB - 1);
    const int ch = blockIdx.x >> 6;            // NRB == 64
    const int i0 = rb * RB + wave * 32;
    const int j0 = ch * CJ;

    const bf16x8 zero8 = {0,0,0,0,0,0,0,0};
    bf16x8 zbi[2];
    float  bi[2];
    #pragma unroll
    for (int t = 0; t < 2; ++t) {
        zbi[t] = (g < 2)
            ? *reinterpret_cast<const bf16x8*>(zb + (size_t)(i0 + t*16 + q) * 16 + g*8)
            : zero8;
        bi[t]  = bbf[i0 + t*16 + q];
    }
    const float nclamp = -(*theta_p) * LOG2E;
    const f32x4 z4 = {0.0f, 0.0f, 0.0f, 0.0f};

    f32x4 H[2][4];
    #pragma unroll
    for (int t = 0; t < 2; ++t)
        #pragma unroll
        for (int nt = 0; nt < 4; ++nt) H[t][nt] = z4;

    unsigned long long* myP = sP + wave * 320;

    for (int jp = 0; jp < CJ / 32; ++jp) {
        // ---- phase 1: QK^T + sigmoid + pack -> LDS (ull writes) ----
        #pragma unroll
        for (int half = 0; half < 2; ++half) {
            const int gj = j0 + jp*32 + half*16;
            bf16x8 za = (g < 2)
                ? *reinterpret_cast<const bf16x8*>(zb + (size_t)(gj + q) * 16 + g*8)
                : zero8;
            f32x4  bj = *reinterpret_cast<const f32x4*>(bbf + gj + 4*g);
            #pragma unroll
            for (int t = 0; t < 2; ++t) {
                f32x4 S = __builtin_amdgcn_mfma_f32_16x16x32_bf16(za, zbi[t], z4, 0, 0, 0);
                unsigned int ur[4];
                #pragma unroll
                for (int r = 0; r < 4; ++r) {
                    float n = (bi[t] + bj[r]) - S[r];
                    n = fmaxf(n, nclamp);
                    float P = __builtin_amdgcn_rcpf(1.0f + __builtin_amdgcn_exp2f(n));
                    if (i0 + t*16 == gj && q == 4*g + r) P = 0.0f;  // diag
                    ur[r] = __float_as_uint(P) + 0x8000u;
                }
                unsigned int pk0 = (ur[0] >> 16) | (ur[1] & 0xFFFF0000u);
                unsigned int pk1 = (ur[2] >> 16) | (ur[3] & 0xFFFF0000u);
                // byte layout: t*1280 + q*80 + half*32 + g*8  (ull index /8)
                myP[t*160 + q*10 + half*4 + g] =
                    ((unsigned long long)pk1 << 32) | pk0;
            }
        }
        __threadfence_block();   // lgkmcnt fence: wave-local LDS writes complete

        // ---- phase 2: LDS -> A-frag (ull reads), PV MFMA ----
        const int jb = j0 + jp*32;
        bf16x8 pa[2];
        #pragma unroll
        for (int t = 0; t < 2; ++t) {
            union { unsigned long long u[2]; bf16x8 v; } pu;
            pu.u[0] = myP[t*160 + q*10 + g*2];      // byte: t*1280 + q*80 + g*16
            pu.u[1] = myP[t*160 + q*10 + g*2 + 1];
            pa[t] = pu.v;
        }
        #pragma unroll
        for (int nt = 0; nt < 4; ++nt) {
            bf16x8 xb = *reinterpret_cast<const bf16x8*>(
                xT + (size_t)(nt*16 + q) * NROWS + jb + g*8);
            H[0][nt] = __builtin_amdgcn_mfma_f32_16x16x32_bf16(pa[0], xb, H[0][nt], 0, 0, 0);
            H[1][nt] = __builtin_amdgcn_mfma_f32_16x16x32_bf16(pa[1], xb, H[1][nt], 0, 0, 0);
        }
    }

    // epilogue: natural-layout flat store, each inst = 256 B contiguous.
    // wave region = rowbase*64 within chunk; chunk base = ch*CHPAD.
    float* regout = hacc + (size_t)ch * CHPAD
                  + (((size_t)(rb * WAVES + wave)) * 32) * 64;
    #pragma unroll
    for (int t = 0; t < 2; ++t)
        #pragma unroll
        for (int nt = 0; nt < 4; ++nt)
            #pragma unroll
            for (int r = 0; r < 4; ++r)
                regout[(t*16 + nt*4 + r) * 64 + lane] = H[t][nt][r];
}

// ---------------------------------------------------------------------------
// K3 (fused reduce + head): block b owns rows [b*16, b*16+16) whose flat
//   partials live at within-chunk float offset b*1024 (16 slots x 64 lanes).
//   Phase A: 256 thr each own one float4; sum over 32 chunks with per-block
//   chunk rotation (de-camp) + padded stride; de-swizzle into LDS h[16][64].
//   Phase B: 16 lanes finish one row each: +x_i/+1, normalize, fc3, fc6,
//   softmax.
//   Decode (f = tid*4): lane=f&63, s=(f>>6)&15;
//   il = (lane>>4)*4 + (s&3); col = ((s>>2)&3)*16 + (lane&15).
// ---------------------------------------------------------------------------
__global__ __launch_bounds__(256) void k3_fused(
    const float* __restrict__ hacc,
    const float* __restrict__ x,
    const float* __restrict__ w3, const float* __restrict__ b3,
    const float* __restrict__ w6, const float* __restrict__ b6,
    float* __restrict__ out)
{
    __shared__ float sh[16][64];

    const int tid = threadIdx.x;
    const int b   = blockIdx.x;

    // ---- phase A: reduce + de-swizzle ----
    {
        const float4* src = reinterpret_cast<const float4*>(
            hacc + (size_t)b * 1024) + tid;
        float4 s = make_float4(0.0f, 0.0f, 0.0f, 0.0f);
        #pragma unroll 8
        for (int cc = 0; cc < NCH; ++cc) {
            int ch = (cc + b) & (NCH - 1);          // rotation: de-camp
            float4 v = src[(size_t)ch * (CHPAD / 4)];
            s.x += v.x; s.y += v.y; s.z += v.z; s.w += v.w;
        }
        const int f    = tid * 4;
        const int lane = f & 63;
        const int slt  = (f >> 6) & 15;
        const int il   = (lane >> 4) * 4 + (slt & 3);
        const int cl   = ((slt >> 2) & 3) * 16 + (lane & 15);
        *reinterpret_cast<float4*>(&sh[il][cl]) = s;
    }
    __syncthreads();

    // ---- phase B: head, one row per lane (16 active) ----
    if (tid < 16) {
        const int row = b * 16 + tid;
        const float* hi = sh[tid];
        const float* xi = x + (size_t)row * DIN;

        float rd = __builtin_amdgcn_rcpf(hi[60] + 1.0f);

        float h[DIN];
        #pragma unroll
        for (int k = 0; k < DIN; ++k) h[k] = (hi[k] + xi[k]) * rd;

        float g[8];
        #pragma unroll
        for (int o = 0; o < 8; ++o) {
            float a = b3[o];
            #pragma unroll
            for (int k = 0; k < DIN; ++k) a = fmaf(w3[o*DIN+k], h[k], a);
            g[o] = a;
        }

        float l[NC];
        float m = -3.0e38f;
        #pragma unroll
        for (int c = 0; c < NC; ++c) {
            float a = b6[c];
            #pragma unroll
            for (int o = 0; o < 8; ++o) a = fmaf(w6[c*8+o], g[o], a);
            l[c] = a;
            m = fmaxf(m, a);
        }
        float e[NC];
        float sum = 0.0f;
        #pragma unroll
        for (int c = 0; c < NC; ++c) {
            e[c] = __builtin_amdgcn_exp2f((l[c] - m) * LOG2E);
            sum += e[c];
        }
        float rsum = __builtin_amdgcn_rcpf(sum);
        #pragma unroll
        for (int c = 0; c < NC; ++c) out[(size_t)row * NC + c] = e[c] * rsum;
    }
}

// ---------------------------------------------------------------------------
extern "C" void kernel_launch(void* const* d_in, const int* in_sizes, int n_in,
                              void* d_out, int out_size, void* d_ws, size_t ws_size,
                              hipStream_t stream)
{
    const float* x     = (const float*)d_in[0];
    const float* w1    = (const float*)d_in[1];
    const float* b1    = (const float*)d_in[2];
    const float* w2    = (const float*)d_in[3];
    const float* b2    = (const float*)d_in[4];
    const float* w3    = (const float*)d_in[5];
    const float* b3    = (const float*)d_in[6];
    const float* w6    = (const float*)d_in[7];
    const float* b6    = (const float*)d_in[8];
    const float* temp  = (const float*)d_in[9];
    const float* theta = (const float*)d_in[10];
    float* out = (float*)d_out;

    // ws carve-up: 256K + 32K + 1M + 64.13 MiB = 68,583,424 B
    // <= 68,714,496 B proven in-use by r7's passing run.
    char* p = (char*)d_ws;
    unsigned short* zbuf = (unsigned short*)p;  p += (size_t)NROWS * 16 * 2;      // 256 KiB
    float*          bbf  = (float*)p;           p += (size_t)NROWS * 4;           // 32 KiB
    unsigned short* xT   = (unsigned short*)p;  p += (size_t)64 * NROWS * 2;      // 1 MiB
    float*          hacc = (float*)p;           // [NCH][CHPAD]

    k1_all  <<<NROWS / 64, 64, 0, stream>>>(x, w1, b1, w2, b2, temp, theta, zbuf, bbf, xT);
    k2_mfma <<<NRB * NCH, 256, 0, stream>>>(zbuf, bbf, xT, theta, hacc);
    k3_fused<<<NROWS / 16, 256, 0, stream>>>(hacc, x, w3, b3, w6, b6, out);
}

// Round 11
// 179.163 us; speedup vs baseline: 1.1636x; 1.0042x over previous
//
#include <hip/hip_runtime.h>
#include <math.h>

#define NROWS 8192
#define DIN   60
#define DZ    16
#define NC    10

#define LOG2E 1.4426950408889634f

// K2 tiling: block = 256 thr (4 waves), each wave owns 32 rows (one 32x32
// i-tile). RB=128 rows/block, CJ=512 cols/chunk -> grid 64*16 = 1024 blocks.
#define RB      128
#define CJ      512
#define NRB     (NROWS / RB)     // 64 row blocks
#define NCH     (NROWS / CJ)     // 16 col chunks
#define WAVES   4
#define REGIONS (NRB * WAVES)    // 256 wave regions of 32 rows

// partials chunk stride: 2 MiB + 4 KiB pad (de-camp power-of-2 stride)
#define CHPAD (NROWS * 64 + 1024)   // floats

typedef short    bf16x8 __attribute__((ext_vector_type(8)));
typedef float    f32x4  __attribute__((ext_vector_type(4)));
typedef float    f32x16 __attribute__((ext_vector_type(16)));
typedef unsigned u32x2  __attribute__((ext_vector_type(2)));

__device__ __forceinline__ unsigned int bfr(float f) {
    // bf16 bits, round-half-up
    return (__float_as_uint(f) + 0x8000u) >> 16;
}

// ---------------------------------------------------------------------------
// K1 (fused): z = fc2(fc1(x)); zb[i][0..15] = bf16(z*sqrt(2*temp*log2e));
// bbf_i = log2e*(temp*||z||^2 - theta/2); xT = bf16 transpose of x augmented
// with a ones-column (row 60).
// ---------------------------------------------------------------------------
__global__ __launch_bounds__(64) void k1_all(
    const float* __restrict__ x,
    const float* __restrict__ w1, const float* __restrict__ b1,
    const float* __restrict__ w2, const float* __restrict__ b2,
    const float* __restrict__ temp_p, const float* __restrict__ theta_p,
    unsigned short* __restrict__ zb, float* __restrict__ bbf,
    unsigned short* __restrict__ xT)
{
    int i = blockIdx.x * 64 + threadIdx.x;

    float xr[DIN];
    const float4* xp = reinterpret_cast<const float4*>(x + (size_t)i * DIN);
    #pragma unroll
    for (int c = 0; c < 15; ++c) {
        float4 v = xp[c];
        xr[c*4+0] = v.x; xr[c*4+1] = v.y; xr[c*4+2] = v.z; xr[c*4+3] = v.w;
    }

    float n1[32];
    #pragma unroll
    for (int o = 0; o < 32; ++o) {
        float acc = b1[o];
        #pragma unroll
        for (int k = 0; k < DIN; ++k) acc = fmaf(w1[o*DIN+k], xr[k], acc);
        n1[o] = acc;
    }

    float z[DZ];
    float sq = 0.0f;
    #pragma unroll
    for (int u = 0; u < DZ; ++u) {
        float acc = b2[u];
        #pragma unroll
        for (int o = 0; o < 32; ++o) acc = fmaf(w2[u*32+o], n1[o], acc);
        z[u] = acc;
        sq = fmaf(acc, acc, sq);
    }

    float temp  = *temp_p;
    float theta = *theta_p;
    float s = sqrtf(2.0f * temp * LOG2E);

    unsigned int p[8];
    #pragma unroll
    for (int u = 0; u < 8; ++u) {
        unsigned int lo = bfr(z[2*u]   * s);
        unsigned int hi = bfr(z[2*u+1] * s);
        p[u] = lo | (hi << 16);
    }
    uint4* dst = reinterpret_cast<uint4*>(zb + (size_t)i * 16);
    dst[0] = make_uint4(p[0], p[1], p[2], p[3]);
    dst[1] = make_uint4(p[4], p[5], p[6], p[7]);

    bbf[i] = LOG2E * fmaf(temp, sq, -0.5f * theta);

    #pragma unroll
    for (int c = 0; c < DIN; ++c)
        xT[(size_t)c * NROWS + i] = (unsigned short)bfr(xr[c]);
    xT[(size_t)60 * NROWS + i] = 0x3F80;  // 1.0
    xT[(size_t)61 * NROWS + i] = 0;
    xT[(size_t)62 * NROWS + i] = 0;
    xT[(size_t)63 * NROWS + i] = 0;
}

// ---------------------------------------------------------------------------
// K2: 32x32x16 MFMA pairwise, LDS-free.
//   QK: S = mfma32(z_j, z_i): lane holds S[jm][ic] for ic=lane&31,
//   jm=(reg&3)+8*(reg>>2)+4*(lane>>5). Score matrix is SYMMETRIC
//   (dot + b_i+b_j), so P[jm][ic] == P[ic][jm]: each lane already owns its
//   PV A-row; only the lane<->lane+32 j-redistribution is needed ->
//   4x permlane32_swap on packed bf16 pairs (T12), no LDS, no fence.
//   PV: H[ic-rows][n] += P @ xT-aug, two K=16 mfmas per 32-j block per nt.
//   Rowsum = col 60. Diag zeroed; k3 re-adds +x_i/+1 exactly in fp32.
//   Epilogue: natural layout [ch(pad)][region][nt*16+reg][lane], 32x256B.
// ---------------------------------------------------------------------------
__global__ __launch_bounds__(256) void k2_mfma(
    const unsigned short* __restrict__ zb, const float* __restrict__ bbf,
    const unsigned short* __restrict__ xT, const float* __restrict__ theta_p,
    float* __restrict__ hacc)   // [NCH][CHPAD] floats
{
    const int tid  = threadIdx.x;
    const int lane = tid & 63, wave = tid >> 6;
    const int ic = lane & 31;      // column within 32-tile (i for B, j for A)
    const int h  = lane >> 5;      // K-half selector
    const int rb = blockIdx.x & (NRB - 1);
    const int ch = blockIdx.x >> 6;          // NRB == 64
    const int it = rb * RB + wave * 32;
    const int j0 = ch * CJ;

    bf16x8 zbi = *reinterpret_cast<const bf16x8*>(zb + (size_t)(it + ic) * 16 + h * 8);
    const float bi = bbf[it + ic];
    const float nclamp = -(*theta_p) * LOG2E;

    // diagonal slot for this lane (used only when i-tile == j-tile)
    const int  dd   = ic - 4 * h;
    const bool dl   = (dd >= 0) && ((dd & 7) < 4);
    const int  dreg = dl ? (((dd >> 3) << 2) | (dd & 3)) : -1;

    f32x16 z16;
    #pragma unroll
    for (int k = 0; k < 16; ++k) z16[k] = 0.0f;
    f32x16 H0 = z16, H1 = z16;

    for (int jb = 0; jb < CJ / 32; ++jb) {
        const int jt = j0 + jb * 32;
        bf16x8 za = *reinterpret_cast<const bf16x8*>(zb + (size_t)(jt + ic) * 16 + h * 8);
        f32x16 S = __builtin_amdgcn_mfma_f32_32x32x16_bf16(za, zbi, z16, 0, 0, 0);

        const bool dblk = (it == jt);
        unsigned pk[8];
        #pragma unroll
        for (int u = 0; u < 4; ++u) {
            f32x4 bj = *reinterpret_cast<const f32x4*>(bbf + jt + u * 8 + 4 * h);
            unsigned ur[4];
            #pragma unroll
            for (int r = 0; r < 4; ++r) {
                const int reg = u * 4 + r;
                float n = (bi + bj[r]) - S[reg];
                n = fmaxf(n, nclamp);
                float P = __builtin_amdgcn_rcpf(1.0f + __builtin_amdgcn_exp2f(n));
                if (dblk && reg == dreg) P = 0.0f;   // diagonal
                ur[r] = __float_as_uint(P) + 0x8000u;
            }
            pk[u*2 + 0] = (ur[0] >> 16) | (ur[1] & 0xFFFF0000u);
            pk[u*2 + 1] = (ur[2] >> 16) | (ur[3] & 0xFFFF0000u);
        }

        // lane<->lane+32 redistribution: assemble PV A-frags in-register
        u32x2 sA = __builtin_amdgcn_permlane32_swap(pk[0], pk[2], false, false);
        u32x2 sB = __builtin_amdgcn_permlane32_swap(pk[1], pk[3], false, false);
        u32x2 sC = __builtin_amdgcn_permlane32_swap(pk[4], pk[6], false, false);
        u32x2 sD = __builtin_amdgcn_permlane32_swap(pk[5], pk[7], false, false);
        union { unsigned u[4]; bf16x8 v; } pa0, pa1;
        pa0.u[0] = sA[0]; pa0.u[1] = sB[0]; pa0.u[2] = sA[1]; pa0.u[3] = sB[1];
        pa1.u[0] = sC[0]; pa1.u[1] = sD[0]; pa1.u[2] = sC[1]; pa1.u[3] = sD[1];

        // PV: j in [jt,jt+16) via pa0, [jt+16,jt+32) via pa1
        {
            bf16x8 xb0 = *reinterpret_cast<const bf16x8*>(
                xT + (size_t)(ic) * NROWS + jt + h*8);
            bf16x8 xb1 = *reinterpret_cast<const bf16x8*>(
                xT + (size_t)(ic) * NROWS + jt + 16 + h*8);
            H0 = __builtin_amdgcn_mfma_f32_32x32x16_bf16(pa0.v, xb0, H0, 0, 0, 0);
            H0 = __builtin_amdgcn_mfma_f32_32x32x16_bf16(pa1.v, xb1, H0, 0, 0, 0);
        }
        {
            bf16x8 xb0 = *reinterpret_cast<const bf16x8*>(
                xT + (size_t)(32 + ic) * NROWS + jt + h*8);
            bf16x8 xb1 = *reinterpret_cast<const bf16x8*>(
                xT + (size_t)(32 + ic) * NROWS + jt + 16 + h*8);
            H1 = __builtin_amdgcn_mfma_f32_32x32x16_bf16(pa0.v, xb0, H1, 0, 0, 0);
            H1 = __builtin_amdgcn_mfma_f32_32x32x16_bf16(pa1.v, xb1, H1, 0, 0, 0);
        }
    }

    // epilogue: natural-layout flat store, 32 insts x 256 B contiguous
    const int region = rb * WAVES + wave;
    float* outp = hacc + (size_t)ch * CHPAD + (size_t)region * 2048;
    #pragma unroll
    for (int reg = 0; reg < 16; ++reg)
        outp[reg * 64 + lane] = H0[reg];
    #pragma unroll
    for (int reg = 0; reg < 16; ++reg)
        outp[(16 + reg) * 64 + lane] = H1[reg];
}

// ---------------------------------------------------------------------------
// K3 (fused reduce + head): block b = (region = b>>1, sub = b&1) owns rows
//   region*32 + sub*16 + [0,16). Phase A: 256 thr each own one float4 of the
//   1024-float sub-span; sum over NCH chunks (rotated, padded stride),
//   de-swizzle into LDS sh[16][64].
//   Decode: nt=tid>>7; foff=(tid&127)*4; rr=foff>>6; lane=foff&63;
//   il=(rr&3)+8*(rr>>2)+4*(lane>>5); col=nt*32+(lane&31);
//   src off = region*2048 + nt*1024 + sub*512 + foff.
//   Phase B: 16 lanes finish one row each: +x_i/+1, normalize, fc3, fc6,
//   softmax.
// ---------------------------------------------------------------------------
__global__ __launch_bounds__(256) void k3_fused(
    const float* __restrict__ hacc,
    const float* __restrict__ x,
    const float* __restrict__ w3, const float* __restrict__ b3,
    const float* __restrict__ w6, const float* __restrict__ b6,
    float* __restrict__ out)
{
    __shared__ float sh[16][64];

    const int tid    = threadIdx.x;
    const int b      = blockIdx.x;
    const int region = b >> 1, sub = b & 1;

    // ---- phase A: reduce + de-swizzle ----
    {
        const int nt   = tid >> 7;
        const int foff = (tid & 127) * 4;
        const int rr   = foff >> 6;
        const int lane = foff & 63;
        const size_t base = (size_t)region * 2048 + nt * 1024 + sub * 512 + foff;

        float4 s = make_float4(0.0f, 0.0f, 0.0f, 0.0f);
        #pragma unroll 4
        for (int cc = 0; cc < NCH; ++cc) {
            int ch = (cc + b) & (NCH - 1);          // rotation: de-camp
            float4 v = *reinterpret_cast<const float4*>(
                hacc + (size_t)ch * CHPAD + base);
            s.x += v.x; s.y += v.y; s.z += v.z; s.w += v.w;
        }
        const int il  = (rr & 3) + 8 * (rr >> 2) + 4 * (lane >> 5);
        const int col = nt * 32 + (lane & 31);
        *reinterpret_cast<float4*>(&sh[il][col]) = s;
    }
    __syncthreads();

    // ---- phase B: head, one row per lane (16 active) ----
    if (tid < 16) {
        const int row = region * 32 + sub * 16 + tid;
        const float* hi = sh[tid];
        const float* xi = x + (size_t)row * DIN;

        float rd = __builtin_amdgcn_rcpf(hi[60] + 1.0f);

        float h[DIN];
        #pragma unroll
        for (int k = 0; k < DIN; ++k) h[k] = (hi[k] + xi[k]) * rd;

        float g[8];
        #pragma unroll
        for (int o = 0; o < 8; ++o) {
            float a = b3[o];
            #pragma unroll
            for (int k = 0; k < DIN; ++k) a = fmaf(w3[o*DIN+k], h[k], a);
            g[o] = a;
        }

        float l[NC];
        float m = -3.0e38f;
        #pragma unroll
        for (int c = 0; c < NC; ++c) {
            float a = b6[c];
            #pragma unroll
            for (int o = 0; o < 8; ++o) a = fmaf(w6[c*8+o], g[o], a);
            l[c] = a;
            m = fmaxf(m, a);
        }
        float e[NC];
        float sum = 0.0f;
        #pragma unroll
        for (int c = 0; c < NC; ++c) {
            e[c] = __builtin_amdgcn_exp2f((l[c] - m) * LOG2E);
            sum += e[c];
        }
        float rsum = __builtin_amdgcn_rcpf(sum);
        #pragma unroll
        for (int c = 0; c < NC; ++c) out[(size_t)row * NC + c] = e[c] * rsum;
    }
}

// ---------------------------------------------------------------------------
extern "C" void kernel_launch(void* const* d_in, const int* in_sizes, int n_in,
                              void* d_out, int out_size, void* d_ws, size_t ws_size,
                              hipStream_t stream)
{
    const float* x     = (const float*)d_in[0];
    const float* w1    = (const float*)d_in[1];
    const float* b1    = (const float*)d_in[2];
    const float* w2    = (const float*)d_in[3];
    const float* b2    = (const float*)d_in[4];
    const float* w3    = (const float*)d_in[5];
    const float* b3    = (const float*)d_in[6];
    const float* w6    = (const float*)d_in[7];
    const float* b6    = (const float*)d_in[8];
    const float* temp  = (const float*)d_in[9];
    const float* theta = (const float*)d_in[10];
    float* out = (float*)d_out;

    // ws carve-up: 256K + 32K + 1M + 16*(2MiB+4KiB) = ~33.6 MiB (<< proven)
    char* p = (char*)d_ws;
    unsigned short* zbuf = (unsigned short*)p;  p += (size_t)NROWS * 16 * 2;      // 256 KiB
    float*          bbf  = (float*)p;           p += (size_t)NROWS * 4;           // 32 KiB
    unsigned short* xT   = (unsigned short*)p;  p += (size_t)64 * NROWS * 2;      // 1 MiB
    float*          hacc = (float*)p;           // [NCH][CHPAD]

    k1_all  <<<NROWS / 64, 64, 0, stream>>>(x, w1, b1, w2, b2, temp, theta, zbuf, bbf, xT);
    k2_mfma <<<NRB * NCH, 256, 0, stream>>>(zbuf, bbf, xT, theta, hacc);
    k3_fused<<<REGIONS * 2, 256, 0, stream>>>(hacc, x, w3, b3, w6, b6, out);
}